// Round 6
// baseline (351.561 us; speedup 1.0000x reference)
//
#include <hip/hip_runtime.h>

typedef __attribute__((ext_vector_type(8))) short s16x8;
typedef __attribute__((ext_vector_type(4))) short s16x4;
typedef __attribute__((ext_vector_type(4))) float f32x4;
typedef __attribute__((ext_vector_type(8))) __bf16 bf16x8;
typedef __attribute__((ext_vector_type(2))) unsigned u32x2;
typedef __attribute__((ext_vector_type(2))) unsigned long long u64x2;

// fp32 -> bf16 round-to-nearest-even
__device__ __forceinline__ short f2b(float f) {
  unsigned u = __float_as_uint(f);
  u += 0x7fffu + ((u >> 16) & 1u);
  return (short)(u >> 16);
}

// pack two fp32 -> two bf16 (truncate) in ONE v_perm_b32
__device__ __forceinline__ unsigned pkb(float lo, float hi) {
  return __builtin_amdgcn_perm(__float_as_uint(hi), __float_as_uint(lo),
                               0x07060302u);
}

__device__ __forceinline__ f32x4 mfma32(s16x8 a, s16x8 b, f32x4 c) {
  return __builtin_amdgcn_mfma_f32_16x16x32_bf16(
      __builtin_bit_cast(bf16x8, a), __builtin_bit_cast(bf16x8, b), c, 0, 0, 0);
}

#if __has_builtin(__builtin_amdgcn_mfma_f32_16x16x16bf16_1k)
#define HAVE_MFMA16 1
__device__ __forceinline__ f32x4 mfma16(s16x4 a, s16x4 b, f32x4 c) {
  return __builtin_amdgcn_mfma_f32_16x16x16bf16_1k(a, b, c, 0, 0, 0);
}
#else
#define HAVE_MFMA16 0
// repack P (S^T C-layout regs, k=16j+quad*4+r) into 16x16x32 A-frag (k=quad*8+c)
__device__ __forceinline__ s16x8 repack(s16x4 pa, s16x4 pb, int quad, int ln15) {
  unsigned long long a = __builtin_bit_cast(unsigned long long, pa);
  unsigned long long bq = __builtin_bit_cast(unsigned long long, pb);
  int srcLo = ((quad & 1) << 5) | ln15;
  unsigned long long loa = __shfl(a, srcLo);
  unsigned long long lob = __shfl(bq, srcLo);
  unsigned long long hia = __shfl(a, srcLo + 16);
  unsigned long long hib = __shfl(bq, srcLo + 16);
  u64x2 t;
  t[0] = quad < 2 ? loa : lob;
  t[1] = quad < 2 ? hia : hib;
  return __builtin_bit_cast(s16x8, t);
}
#endif

// ---------------- convert fp32 -> bf16 (x, Wq|Wk|Wv concat, Wo) ----------------
__global__ __launch_bounds__(256) void convert_all(
    const float* __restrict__ x, const float* __restrict__ wq,
    const float* __restrict__ wk, const float* __restrict__ wv,
    const float* __restrict__ wo, short* __restrict__ xb,
    short* __restrict__ wqkvb, short* __restrict__ wob) {
  size_t i4 = ((size_t)blockIdx.x * 256 + threadIdx.x) * 4;
  const float* src;
  short* dst;
  size_t off;
  if (i4 < 8388608) {
    src = x; dst = xb; off = i4;
  } else if (i4 < 9437184) {
    src = wq; dst = wqkvb; off = i4 - 8388608;
  } else if (i4 < 10485760) {
    src = wk; dst = wqkvb + 1048576; off = i4 - 9437184;
  } else if (i4 < 11534336) {
    src = wv; dst = wqkvb + 2097152; off = i4 - 10485760;
  } else {
    src = wo; dst = wob; off = i4 - 11534336;
  }
  float4 f = *(const float4*)(src + off);
  s16x4 o;
  o[0] = f2b(f.x); o[1] = f2b(f.y); o[2] = f2b(f.z); o[3] = f2b(f.w);
  *(s16x4*)(dst + off) = o;
}

// ---------------- GEMM: C[M,N] = A[M,K] * B[N,K]^T  (m97 structure) ----------
__device__ __forceinline__ void stage_tile(const short* __restrict__ g, int ld,
                                           int row0, int k0, short* lds,
                                           int wid, int lane) {
#pragma unroll
  for (int i = 0; i < 2; ++i) {
    int e = i * 2048 + wid * 512 + lane * 8;
    int row = e >> 5, col = e & 31;
    const short* gp = g + (size_t)(row0 + row) * ld + k0 + col;
    __builtin_amdgcn_global_load_lds(
        (const __attribute__((address_space(1))) void*)gp,
        (__attribute__((address_space(3))) void*)(lds + i * 2048 + wid * 512),
        16, 0, 0);
  }
}

// EPI 0: scatter QKV -> Q (pre-scaled by log2e/8), K, V, all bf16 [B,H,T,D],
//        via LDS-coalesced epilogue (16B contiguous stores).
// EPI 1: fp32 direct store.
template <int EPI>
__global__ __launch_bounds__(256) void gemm_bt(
    const short* __restrict__ A, const short* __restrict__ Bw,
    float* __restrict__ outf, short* __restrict__ qkv,
    int M, int N, int K) {
  // overlay: lA/lB (16 KB) for K-loop; lC (128x132 shorts = 33 KB) for epilogue
  __shared__ __align__(16) char smem[EPI == 0 ? 128 * 132 * 2 : 16384];
  short* lA = (short*)smem;
  short* lB = lA + 4096;
  const int tid = threadIdx.x;
  const int lane = tid & 63, wid = tid >> 6;
  const int quad = lane >> 4, ln15 = lane & 15;
  const int wm = wid & 1, wn = wid >> 1;
  const int m0 = blockIdx.y * 128, n0 = blockIdx.x * 128;

  f32x4 acc[4][4] = {};

  stage_tile(A, K, m0, 0, lA, wid, lane);
  stage_tile(Bw, K, n0, 0, lB, wid, lane);

  const int nk = K >> 5;
  for (int kt = 0; kt < nk; ++kt) {
    __syncthreads();
    s16x8 af[4], bf[4];
#pragma unroll
    for (int i = 0; i < 4; ++i)
      af[i] = *(const s16x8*)&lA[(wm * 64 + i * 16 + ln15) * 32 + quad * 8];
#pragma unroll
    for (int j = 0; j < 4; ++j)
      bf[j] = *(const s16x8*)&lB[(wn * 64 + j * 16 + ln15) * 32 + quad * 8];
#pragma unroll
    for (int i = 0; i < 4; ++i)
#pragma unroll
      for (int j = 0; j < 4; ++j)
        acc[i][j] = mfma32(af[i], bf[j], acc[i][j]);
    __syncthreads();
    if (kt + 1 < nk) {
      stage_tile(A, K, m0, (kt + 1) << 5, lA, wid, lane);
      stage_tile(Bw, K, n0, (kt + 1) << 5, lB, wid, lane);
    }
  }

  if (EPI == 1) {
#pragma unroll
    for (int i = 0; i < 4; ++i)
#pragma unroll
      for (int j = 0; j < 4; ++j)
#pragma unroll
        for (int r = 0; r < 4; ++r) {
          int m = m0 + wm * 64 + i * 16 + quad * 4 + r;
          int n = n0 + wn * 64 + j * 16 + ln15;
          outf[(size_t)m * N + n] = acc[i][j][r];
        }
  } else {
    const float QSC = 0.18033688f;  // (1/sqrt(64)) * log2(e), folded into Q
    const int which = n0 >> 10;     // whole 128-tile within one of Q/K/V
    const float sf = (which == 0) ? QSC : 1.0f;
    short* lC = (short*)smem;
    __syncthreads();  // all waves done with lA/lB ds_reads
#pragma unroll
    for (int i = 0; i < 4; ++i)
#pragma unroll
      for (int j = 0; j < 4; ++j) {
        int mm = wm * 64 + i * 16 + quad * 4;
        int nn = wn * 64 + j * 16 + ln15;
#pragma unroll
        for (int r = 0; r < 4; ++r)
          lC[(mm + r) * 132 + nn] = f2b(acc[i][j][r] * sf);
      }
    __syncthreads();
    short* outb = qkv + (size_t)which * 8388608;
#pragma unroll
    for (int r0 = 0; r0 < 8; ++r0) {
      int m = r0 * 16 + (tid >> 4);
      int ncol = (tid & 15) * 8;
      s16x4 lo = *(const s16x4*)&lC[m * 132 + ncol];
      s16x4 hi = *(const s16x4*)&lC[m * 132 + ncol + 4];
      s16x8 v8;
#pragma unroll
      for (int z = 0; z < 4; ++z) { v8[z] = lo[z]; v8[4 + z] = hi[z]; }
      int n = n0 + ncol;
      int mg = m0 + m;
      int bidx = mg >> 11, t = mg & 2047;
      int hh = (n >> 6) & 15, d0 = n & 63;
      *(s16x8*)&outb[(size_t)((((bidx << 4) + hh) << 11) + t) * 64 + d0] = v8;
    }
  }
}

// ---------------- flash attention, S^T form, fixed-max ----------------------
// Uniform work via intra-block pairing (the only balancer that doesn't depend
// on undefined block->CU mapping): per (b,h), 16 chunks of 128 q rows; block
// handles (15-p, p) as two phases. 512 blocks, 2/CU, 4 waves x 32 q rows.
// 128 KV rows per barrier round (two 64-tiles staged together, computed
// back-to-back) -> 17 rounds/block instead of 36. Measured r2/r3: per-round
// serial cost ~2.3-2.7us nearly independent of round width => fixed per-round
// latency dominates; halving rounds attacks it directly.
// K staged via global_load_lds DMA (double-buffered pairs, XOR-swizzled source
// so ds_read_b128 is conflict-free; zero VGPR cost). V reg-prefetched then
// written transposed [d][t pad VST=74] (odd bank multiplier -> 0 conflicts,
// proven in r4). Fixed max: Q pre-scaled by log2e/8 -> p = exp2(s). l via
// MFMA vs ones. Waves 0,1 skip dead half-tiles; diagonal masked per wave.
__device__ __forceinline__ void stage_k(const short* __restrict__ Kb, int t64,
                                        short* sbuf, int wid, int lane) {
  // LDS linear dest; source granule XOR-swizzled: LDS[row][j] = K[row][j^(row&7)]
#pragma unroll
  for (int i = 0; i < 2; ++i) {
    int g = wid * 128 + i * 64 + lane;      // 16B granule index, 512 total
    int row = g >> 3;
    int sg = (g & 7) ^ (row & 7);
    const short* gp = Kb + (size_t)(t64 * 64 + row) * 64 + sg * 8;
    __builtin_amdgcn_global_load_lds(
        (const __attribute__((address_space(1))) void*)gp,
        (__attribute__((address_space(3))) void*)(sbuf + wid * 1024 + i * 512),
        16, 0, 0);
  }
}

#define VST 74  // V LDS row stride (shorts); odd bank multiplier -> 0 conflicts

__global__ __launch_bounds__(256, 2) void attn_fa(
    const short* __restrict__ Q, const short* __restrict__ K,
    const short* __restrict__ V, short* __restrict__ Aout) {
  __shared__ __align__(16) short sVt[2][2][64 * VST];  // 37 KB
  __shared__ __align__(16) short sK[2][2][4096];       // 32 KB
  const int tid = threadIdx.x;
  const int lane = tid & 63, wid = tid >> 6;
  const int quad = lane >> 4, ln15 = lane & 15;
  const int e3 = ln15 & 7;
  const int bx = blockIdx.x;
  const int bh = bx & 63;  // bh-minor: all blocks of a bh land on one XCD's L2
  const int p = bx >> 6;   // 0..7
  const short* Qb = Q + (size_t)bh * 131072;
  const short* Kb = K + (size_t)bh * 131072;
  const short* Vb = V + (size_t)bh * 131072;
  const int b = bh >> 4, h = bh & 15;
  const int tp = tid & 31, dgrp = tid >> 5;  // V staging: t=2tp,2tp+1; d0=dgrp*4

  for (int ph = 0; ph < 2; ++ph) {
    const int c = ph ? p : (15 - p);         // chunk id (128 q rows)
    const int nr = c + 1;                    // 128-KV-row rounds
    const int ntw = 2 * c + 1 + (wid >> 1);  // this wave's live 64-tiles
    const int qw = c * 128 + wid * 32;       // this wave's 32 q rows

    // Q fragments for this chunk
    s16x8 qf[2][2];
#pragma unroll
    for (int qo = 0; qo < 2; ++qo)
#pragma unroll
      for (int ks = 0; ks < 2; ++ks)
        qf[qo][ks] =
            *(const s16x8*)&Qb[(qw + qo * 16 + ln15) * 64 + ks * 32 + quad * 8];

    f32x4 o[2][4] = {};
    f32x4 lacc[2] = {};

    __syncthreads();  // prior phase's LDS reads done before restaging
    // stage V 64-tiles 0,1 -> buf 0 (transposed, packed b32 writes)
#pragma unroll
    for (int hf = 0; hf < 2; ++hf)
#pragma unroll
      for (int i = 0; i < 2; ++i) {
        int d0 = dgrp * 4 + i * 32;
        s16x4 va0 = *(const s16x4*)&Vb[(hf * 64 + 2 * tp) * 64 + d0];
        s16x4 vb0 = *(const s16x4*)&Vb[(hf * 64 + 2 * tp + 1) * 64 + d0];
#pragma unroll
        for (int u = 0; u < 4; ++u) {
          unsigned w = (unsigned)(unsigned short)va0[u] |
                       ((unsigned)(unsigned short)vb0[u] << 16);
          *(unsigned*)&sVt[0][hf][(d0 + u) * VST + 2 * tp] = w;
        }
      }
    // DMA K 64-tiles 0,1 -> buf 0 (drained by first in-loop barrier)
    stage_k(Kb, 0, sK[0][0], wid, lane);
    stage_k(Kb, 1, sK[0][1], wid, lane);

    for (int kt = 0; kt < nr; ++kt) {
      __syncthreads();  // drains K DMA (vmcnt0) + makes V writes visible
      const int cur = kt & 1;
      const bool nxt = (kt + 1 < nr);
      // prefetch next round's V (both halves) into regs, then DMA next K pair
      s16x4 va[2][2], vbr[2][2];
      if (nxt) {
#pragma unroll
        for (int hf = 0; hf < 2; ++hf)
#pragma unroll
          for (int i = 0; i < 2; ++i) {
            int d0 = dgrp * 4 + i * 32;
            int tr = (2 * (kt + 1) + hf) * 64 + 2 * tp;
            va[hf][i] = *(const s16x4*)&Vb[(size_t)tr * 64 + d0];
            vbr[hf][i] = *(const s16x4*)&Vb[(size_t)(tr + 1) * 64 + d0];
          }
        stage_k(Kb, 2 * (kt + 1), sK[cur ^ 1][0], wid, lane);
        stage_k(Kb, 2 * (kt + 1) + 1, sK[cur ^ 1][1], wid, lane);
      }
      // ---- compute the two 64-tiles of this round ----
#pragma unroll
      for (int hf = 0; hf < 2; ++hf) {
        const int ht = 2 * kt + hf;  // global 64-tile index
        if (ht < ntw) {
          const short* kbuf = sK[cur][hf];
          const short* bufc = sVt[cur][hf];
          __builtin_amdgcn_s_setprio(1);
          // ---- S^T = K Q^T (K from swizzled LDS) ----
          f32x4 s[2][4] = {};
#pragma unroll
          for (int jm = 0; jm < 4; ++jm) {
            const short* kr = &kbuf[(jm * 16 + ln15) * 64];
            s16x8 k0 = *(const s16x8*)&kr[(quad ^ e3) * 8];
            s16x8 k1 = *(const s16x8*)&kr[((4 + quad) ^ e3) * 8];
            s[0][jm] = mfma32(k0, qf[0][0], s[0][jm]);
            s[0][jm] = mfma32(k1, qf[0][1], s[0][jm]);
            s[1][jm] = mfma32(k0, qf[1][0], s[1][jm]);
            s[1][jm] = mfma32(k1, qf[1][1], s[1][jm]);
          }
          __builtin_amdgcn_s_setprio(0);
          // ---- causal mask (diagonal tile only) ----
          if (ht == ntw - 1) {
#pragma unroll
            for (int qo = 0; qo < 2; ++qo) {
              int qg = qw + qo * 16 + ln15;
#pragma unroll
              for (int jm = 0; jm < 4; ++jm) {
                int kg = ht * 64 + jm * 16 + quad * 4;
#pragma unroll
                for (int r = 0; r < 4; ++r)
                  if (kg + r > qg) s[qo][jm][r] = -3e38f;
              }
            }
          }
          // ---- p = exp2(s), pack via v_perm ----
          s16x4 pk[2][4];
#pragma unroll
          for (int qo = 0; qo < 2; ++qo)
#pragma unroll
            for (int jm = 0; jm < 4; ++jm) {
              float p0 = __builtin_amdgcn_exp2f(s[qo][jm][0]);
              float p1 = __builtin_amdgcn_exp2f(s[qo][jm][1]);
              float p2 = __builtin_amdgcn_exp2f(s[qo][jm][2]);
              float p3 = __builtin_amdgcn_exp2f(s[qo][jm][3]);
              u32x2 w2;
              w2[0] = pkb(p0, p1);
              w2[1] = pkb(p2, p3);
              pk[qo][jm] = __builtin_bit_cast(s16x4, w2);
            }
          // ---- O += P V; l += P 1 (both MFMA) ----
          __builtin_amdgcn_s_setprio(1);
#if HAVE_MFMA16
          const s16x4 ones = {16256, 16256, 16256, 16256};  // bf16 1.0
#pragma unroll
          for (int js = 0; js < 4; ++js) {
            lacc[0] = mfma16(pk[0][js], ones, lacc[0]);
            lacc[1] = mfma16(pk[1][js], ones, lacc[1]);
#pragma unroll
            for (int jd = 0; jd < 4; ++jd) {
              s16x4 vf = *(const s16x4*)&bufc[(jd * 16 + ln15) * VST +
                                              js * 16 + quad * 4];
              o[0][jd] = mfma16(pk[0][js], vf, o[0][jd]);
              o[1][jd] = mfma16(pk[1][js], vf, o[1][jd]);
            }
          }
#else
          const s16x8 ones8 = {16256, 16256, 16256, 16256,
                               16256, 16256, 16256, 16256};
#pragma unroll
          for (int ks = 0; ks < 2; ++ks) {
            s16x8 a0 = repack(pk[0][2 * ks], pk[0][2 * ks + 1], quad, ln15);
            s16x8 a1 = repack(pk[1][2 * ks], pk[1][2 * ks + 1], quad, ln15);
            lacc[0] = mfma32(a0, ones8, lacc[0]);
            lacc[1] = mfma32(a1, ones8, lacc[1]);
#pragma unroll
            for (int jd = 0; jd < 4; ++jd) {
              s16x8 vf = *(const s16x8*)&bufc[(jd * 16 + ln15) * VST +
                                              ks * 32 + quad * 8];
              o[0][jd] = mfma32(a0, vf, o[0][jd]);
              o[1][jd] = mfma32(a1, vf, o[1][jd]);
            }
          }
#endif
          __builtin_amdgcn_s_setprio(0);
        }
      }
      // write prefetched V pair -> other buffer
      if (nxt) {
#pragma unroll
        for (int hf = 0; hf < 2; ++hf) {
          short* bufn = sVt[cur ^ 1][hf];
#pragma unroll
          for (int i = 0; i < 2; ++i) {
            int d0 = dgrp * 4 + i * 32;
#pragma unroll
            for (int u = 0; u < 4; ++u) {
              unsigned w = (unsigned)(unsigned short)va[hf][i][u] |
                           ((unsigned)(unsigned short)vbr[hf][i][u] << 16);
              *(unsigned*)&bufn[(d0 + u) * VST + 2 * tp] = w;
            }
          }
        }
      }
    }
    // epilogue: rows q=quad*4+r, cols d=jd*16+ln15; l per-lane from lacc
#pragma unroll
    for (int qo = 0; qo < 2; ++qo)
#pragma unroll
      for (int r = 0; r < 4; ++r) {
        float linv = 1.f / lacc[qo][r];
        int qg = qw + qo * 16 + quad * 4 + r;
        size_t row = ((size_t)b * 2048 + qg) * 1024 + h * 64;
#pragma unroll
        for (int jd = 0; jd < 4; ++jd)
          Aout[row + jd * 16 + ln15] = f2b(o[qo][jd][r] * linv);
      }
  }
}

extern "C" void kernel_launch(void* const* d_in, const int* in_sizes, int n_in,
                              void* d_out, int out_size, void* d_ws, size_t ws_size,
                              hipStream_t stream) {
  const float* x  = (const float*)d_in[0];
  const float* wq = (const float*)d_in[1];
  const float* wk = (const float*)d_in[2];
  const float* wv = (const float*)d_in[3];
  const float* wo = (const float*)d_in[4];
  char* ws = (char*)d_ws;
  short* xb    = (short*)(ws);
  short* wqkvb = (short*)(ws + 16777216);
  short* wob   = (short*)(ws + 23068672);
  short* qkv   = (short*)(ws + 25165824);
  short* attn  = xb;  // x dead after QKV GEMM

  convert_all<<<12288, 256, 0, stream>>>(x, wq, wk, wv, wo, xb, wqkvb, wob);
  gemm_bt<0><<<dim3(24, 64), 256, 0, stream>>>(xb, wqkvb, nullptr, qkv,
                                               8192, 3072, 1024);
  attn_fa<<<512, 256, 0, stream>>>(qkv, qkv + 8388608, qkv + 16777216, attn);
  gemm_bt<1><<<dim3(8, 64), 256, 0, stream>>>(attn, wob, (float*)d_out, nullptr,
                                              8192, 1024, 1024);
}

// Round 7
// 322.726 us; speedup vs baseline: 1.0894x; 1.0894x over previous
//
#include <hip/hip_runtime.h>

typedef __attribute__((ext_vector_type(8))) short s16x8;
typedef __attribute__((ext_vector_type(4))) short s16x4;
typedef __attribute__((ext_vector_type(4))) float f32x4;
typedef __attribute__((ext_vector_type(8))) __bf16 bf16x8;
typedef __attribute__((ext_vector_type(2))) unsigned u32x2;
typedef __attribute__((ext_vector_type(2))) unsigned long long u64x2;

// fp32 -> bf16 round-to-nearest-even
__device__ __forceinline__ short f2b(float f) {
  unsigned u = __float_as_uint(f);
  u += 0x7fffu + ((u >> 16) & 1u);
  return (short)(u >> 16);
}

// pack two fp32 -> two bf16 (truncate) in ONE v_perm_b32
__device__ __forceinline__ unsigned pkb(float lo, float hi) {
  return __builtin_amdgcn_perm(__float_as_uint(hi), __float_as_uint(lo),
                               0x07060302u);
}

__device__ __forceinline__ f32x4 mfma32(s16x8 a, s16x8 b, f32x4 c) {
  return __builtin_amdgcn_mfma_f32_16x16x32_bf16(
      __builtin_bit_cast(bf16x8, a), __builtin_bit_cast(bf16x8, b), c, 0, 0, 0);
}

#if __has_builtin(__builtin_amdgcn_mfma_f32_16x16x16bf16_1k)
#define HAVE_MFMA16 1
__device__ __forceinline__ f32x4 mfma16(s16x4 a, s16x4 b, f32x4 c) {
  return __builtin_amdgcn_mfma_f32_16x16x16bf16_1k(a, b, c, 0, 0, 0);
}
#else
#define HAVE_MFMA16 0
// repack P (S^T C-layout regs, k=16j+quad*4+r) into 16x16x32 A-frag (k=quad*8+c)
__device__ __forceinline__ s16x8 repack(s16x4 pa, s16x4 pb, int quad, int ln15) {
  unsigned long long a = __builtin_bit_cast(unsigned long long, pa);
  unsigned long long bq = __builtin_bit_cast(unsigned long long, pb);
  int srcLo = ((quad & 1) << 5) | ln15;
  unsigned long long loa = __shfl(a, srcLo);
  unsigned long long lob = __shfl(bq, srcLo);
  unsigned long long hia = __shfl(a, srcLo + 16);
  unsigned long long hib = __shfl(bq, srcLo + 16);
  u64x2 t;
  t[0] = quad < 2 ? loa : lob;
  t[1] = quad < 2 ? hia : hib;
  return __builtin_bit_cast(s16x8, t);
}
#endif

// ---------------- convert fp32 -> bf16 (x, Wq|Wk|Wv concat, Wo) ----------------
__global__ __launch_bounds__(256) void convert_all(
    const float* __restrict__ x, const float* __restrict__ wq,
    const float* __restrict__ wk, const float* __restrict__ wv,
    const float* __restrict__ wo, short* __restrict__ xb,
    short* __restrict__ wqkvb, short* __restrict__ wob) {
  size_t i4 = ((size_t)blockIdx.x * 256 + threadIdx.x) * 4;
  const float* src;
  short* dst;
  size_t off;
  if (i4 < 8388608) {
    src = x; dst = xb; off = i4;
  } else if (i4 < 9437184) {
    src = wq; dst = wqkvb; off = i4 - 8388608;
  } else if (i4 < 10485760) {
    src = wk; dst = wqkvb + 1048576; off = i4 - 9437184;
  } else if (i4 < 11534336) {
    src = wv; dst = wqkvb + 2097152; off = i4 - 10485760;
  } else {
    src = wo; dst = wob; off = i4 - 11534336;
  }
  float4 f = *(const float4*)(src + off);
  s16x4 o;
  o[0] = f2b(f.x); o[1] = f2b(f.y); o[2] = f2b(f.z); o[3] = f2b(f.w);
  *(s16x4*)(dst + off) = o;
}

// ---------------- GEMM: C[M,N] = A[M,K] * B[N,K]^T  (m97 structure) ----------
__device__ __forceinline__ void stage_tile(const short* __restrict__ g, int ld,
                                           int row0, int k0, short* lds,
                                           int wid, int lane) {
#pragma unroll
  for (int i = 0; i < 2; ++i) {
    int e = i * 2048 + wid * 512 + lane * 8;
    int row = e >> 5, col = e & 31;
    const short* gp = g + (size_t)(row0 + row) * ld + k0 + col;
    __builtin_amdgcn_global_load_lds(
        (const __attribute__((address_space(1))) void*)gp,
        (__attribute__((address_space(3))) void*)(lds + i * 2048 + wid * 512),
        16, 0, 0);
  }
}

// EPI 0: scatter QKV -> Q (pre-scaled by log2e/8), K, V, all bf16 [B,H,T,D],
//        via LDS-coalesced epilogue (16B contiguous stores).
// EPI 1: fp32 direct store.
template <int EPI>
__global__ __launch_bounds__(256) void gemm_bt(
    const short* __restrict__ A, const short* __restrict__ Bw,
    float* __restrict__ outf, short* __restrict__ qkv,
    int M, int N, int K) {
  // overlay: lA/lB (16 KB) for K-loop; lC (128x132 shorts = 33 KB) for epilogue
  __shared__ __align__(16) char smem[EPI == 0 ? 128 * 132 * 2 : 16384];
  short* lA = (short*)smem;
  short* lB = lA + 4096;
  const int tid = threadIdx.x;
  const int lane = tid & 63, wid = tid >> 6;
  const int quad = lane >> 4, ln15 = lane & 15;
  const int wm = wid & 1, wn = wid >> 1;
  const int m0 = blockIdx.y * 128, n0 = blockIdx.x * 128;

  f32x4 acc[4][4] = {};

  stage_tile(A, K, m0, 0, lA, wid, lane);
  stage_tile(Bw, K, n0, 0, lB, wid, lane);

  const int nk = K >> 5;
  for (int kt = 0; kt < nk; ++kt) {
    __syncthreads();
    s16x8 af[4], bf[4];
#pragma unroll
    for (int i = 0; i < 4; ++i)
      af[i] = *(const s16x8*)&lA[(wm * 64 + i * 16 + ln15) * 32 + quad * 8];
#pragma unroll
    for (int j = 0; j < 4; ++j)
      bf[j] = *(const s16x8*)&lB[(wn * 64 + j * 16 + ln15) * 32 + quad * 8];
#pragma unroll
    for (int i = 0; i < 4; ++i)
#pragma unroll
      for (int j = 0; j < 4; ++j)
        acc[i][j] = mfma32(af[i], bf[j], acc[i][j]);
    __syncthreads();
    if (kt + 1 < nk) {
      stage_tile(A, K, m0, (kt + 1) << 5, lA, wid, lane);
      stage_tile(Bw, K, n0, (kt + 1) << 5, lB, wid, lane);
    }
  }

  if (EPI == 1) {
#pragma unroll
    for (int i = 0; i < 4; ++i)
#pragma unroll
      for (int j = 0; j < 4; ++j)
#pragma unroll
        for (int r = 0; r < 4; ++r) {
          int m = m0 + wm * 64 + i * 16 + quad * 4 + r;
          int n = n0 + wn * 64 + j * 16 + ln15;
          outf[(size_t)m * N + n] = acc[i][j][r];
        }
  } else {
    const float QSC = 0.18033688f;  // (1/sqrt(64)) * log2(e), folded into Q
    const int which = n0 >> 10;     // whole 128-tile within one of Q/K/V
    const float sf = (which == 0) ? QSC : 1.0f;
    short* lC = (short*)smem;
    __syncthreads();  // all waves done with lA/lB ds_reads
#pragma unroll
    for (int i = 0; i < 4; ++i)
#pragma unroll
      for (int j = 0; j < 4; ++j) {
        int mm = wm * 64 + i * 16 + quad * 4;
        int nn = wn * 64 + j * 16 + ln15;
#pragma unroll
        for (int r = 0; r < 4; ++r)
          lC[(mm + r) * 132 + nn] = f2b(acc[i][j][r] * sf);
      }
    __syncthreads();
    short* outb = qkv + (size_t)which * 8388608;
#pragma unroll
    for (int r0 = 0; r0 < 8; ++r0) {
      int m = r0 * 16 + (tid >> 4);
      int ncol = (tid & 15) * 8;
      s16x4 lo = *(const s16x4*)&lC[m * 132 + ncol];
      s16x4 hi = *(const s16x4*)&lC[m * 132 + ncol + 4];
      s16x8 v8;
#pragma unroll
      for (int z = 0; z < 4; ++z) { v8[z] = lo[z]; v8[4 + z] = hi[z]; }
      int n = n0 + ncol;
      int mg = m0 + m;
      int bidx = mg >> 11, t = mg & 2047;
      int hh = (n >> 6) & 15, d0 = n & 63;
      *(s16x8*)&outb[(size_t)((((bidx << 4) + hh) << 11) + t) * 64 + d0] = v8;
    }
  }
}

// ---------------- flash attention, S^T form, fixed-max ----------------------
// Exact r3 structure (best verified: 82us): intra-block causal pairing (block
// handles chunks (15-p, p) as two phases -> identical work per block, robust
// to undefined block->CU mapping), 512 blocks, 4 waves x 32 q rows.
// ONE change vs r3: V LDS layout. VST=74 (r4/r6) made half the b64 PV reads
// 4B-misaligned -> ~2x kernel slowdown (conflict counter blind to it). New
// layout: [d][64] rows (no pad, 8B-aligned) with granule XOR swizzle
// g -> g^(d&15). Writes: bank-bijective per half-wave. PV b64 reads: each
// granule value hit exactly 4x across 64 lanes = structural minimum ->
// conflict-free AND aligned (impossible with any padding).
// K staged via global_load_lds DMA (double-buffered, XOR-swizzled source so
// ds_read_b128 is conflict-free; zero VGPR cost).
// Fixed max: Q pre-scaled by log2e/8 -> p = exp2(s). l via MFMA vs ones.
__device__ __forceinline__ void stage_k(const short* __restrict__ Kb, int t,
                                        short* sbuf, int wid, int lane) {
  // LDS linear dest; source granule XOR-swizzled: LDS[row][j] = K[row][j^(row&7)]
#pragma unroll
  for (int i = 0; i < 2; ++i) {
    int g = wid * 128 + i * 64 + lane;      // 16B granule index, 512 total
    int row = g >> 3;
    int sg = (g & 7) ^ (row & 7);
    const short* gp = Kb + (size_t)(t * 64 + row) * 64 + sg * 8;
    __builtin_amdgcn_global_load_lds(
        (const __attribute__((address_space(1))) void*)gp,
        (__attribute__((address_space(3))) void*)(sbuf + wid * 1024 + i * 512),
        16, 0, 0);
  }
}

__global__ __launch_bounds__(256, 4) void attn_fa(
    const short* __restrict__ Q, const short* __restrict__ K,
    const short* __restrict__ V, short* __restrict__ Aout) {
  __shared__ __align__(16) short sVt[2][64 * 64];  // 16 KB, granule-swizzled
  __shared__ __align__(16) short sK[2][64 * 64];   // 16 KB
  const int tid = threadIdx.x;
  const int lane = tid & 63, wid = tid >> 6;
  const int quad = lane >> 4, ln15 = lane & 15;
  const int e3 = ln15 & 7;
  const int bx = blockIdx.x;
  const int bh = bx & 63;  // bh-minor: all blocks of a bh land on one XCD's L2
  const int p = bx >> 6;   // 0..7
  const short* Qb = Q + (size_t)bh * 131072;
  const short* Kb = K + (size_t)bh * 131072;
  const short* Vb = V + (size_t)bh * 131072;
  const int b = bh >> 4, h = bh & 15;
  const int tp = tid & 31, dgrp = tid >> 5;  // V staging: t=2tp,2tp+1; d0=dgrp*4

  for (int ph = 0; ph < 2; ++ph) {
    const int c = ph ? p : (15 - p);         // chunk id (128 q rows)
    const int nkv = 2 * c + 2;               // uniform barrier count
    const int ntw = 2 * c + 1 + (wid >> 1);  // this wave's live tiles
    const int qw = c * 128 + wid * 32;       // this wave's 32 q rows

    // Q fragments for this chunk
    s16x8 qf[2][2];
#pragma unroll
    for (int qo = 0; qo < 2; ++qo)
#pragma unroll
      for (int ks = 0; ks < 2; ++ks)
        qf[qo][ks] =
            *(const s16x8*)&Qb[(qw + qo * 16 + ln15) * 64 + ks * 32 + quad * 8];

    f32x4 o[2][4] = {};
    f32x4 lacc[2] = {};

    __syncthreads();  // prior phase's LDS reads done before restaging
    // stage V tile 0 -> buf 0 (transposed, granule-swizzled b32 writes)
#pragma unroll
    for (int i = 0; i < 2; ++i) {
      int d0 = dgrp * 4 + i * 32;
      s16x4 va0 = *(const s16x4*)&Vb[(2 * tp) * 64 + d0];
      s16x4 vb0 = *(const s16x4*)&Vb[(2 * tp + 1) * 64 + d0];
#pragma unroll
      for (int u = 0; u < 4; ++u) {
        unsigned w = (unsigned)(unsigned short)va0[u] |
                     ((unsigned)(unsigned short)vb0[u] << 16);
        int dd = d0 + u;
        *(unsigned*)&sVt[0][dd * 64 + (((tp >> 1) ^ (dd & 15)) << 2) +
                            ((tp & 1) << 1)] = w;
      }
    }
    // DMA K tile 0 -> buf 0 (drained by first in-loop barrier)
    stage_k(Kb, 0, sK[0], wid, lane);

    for (int kt = 0; kt < nkv; ++kt) {
      __syncthreads();  // drains K DMA (vmcnt0) + makes V writes visible
      const short* bufc = sVt[kt & 1];
      const short* kbuf = sK[kt & 1];
      const bool nxt = (kt + 1 < nkv);
      // prefetch next V tile into regs + DMA next K tile
      s16x4 va[2], vbr[2];
      if (nxt) {
#pragma unroll
        for (int i = 0; i < 2; ++i) {
          int d0 = dgrp * 4 + i * 32;
          va[i] = *(const s16x4*)&Vb[((kt + 1) * 64 + 2 * tp) * 64 + d0];
          vbr[i] = *(const s16x4*)&Vb[((kt + 1) * 64 + 2 * tp + 1) * 64 + d0];
        }
        stage_k(Kb, kt + 1, sK[(kt + 1) & 1], wid, lane);
      }
      if (kt < ntw) {
        __builtin_amdgcn_s_setprio(1);
        // ---- S^T = K Q^T (K from swizzled LDS) ----
        f32x4 s[2][4] = {};
#pragma unroll
        for (int jm = 0; jm < 4; ++jm) {
          const short* kr = &kbuf[(jm * 16 + ln15) * 64];
          s16x8 k0 = *(const s16x8*)&kr[(quad ^ e3) * 8];
          s16x8 k1 = *(const s16x8*)&kr[((4 + quad) ^ e3) * 8];
          s[0][jm] = mfma32(k0, qf[0][0], s[0][jm]);
          s[0][jm] = mfma32(k1, qf[0][1], s[0][jm]);
          s[1][jm] = mfma32(k0, qf[1][0], s[1][jm]);
          s[1][jm] = mfma32(k1, qf[1][1], s[1][jm]);
        }
        __builtin_amdgcn_s_setprio(0);
        // ---- causal mask (diagonal tile only) ----
        if (kt == ntw - 1) {
#pragma unroll
          for (int qo = 0; qo < 2; ++qo) {
            int qg = qw + qo * 16 + ln15;
#pragma unroll
            for (int jm = 0; jm < 4; ++jm) {
              int kg = kt * 64 + jm * 16 + quad * 4;
#pragma unroll
              for (int r = 0; r < 4; ++r)
                if (kg + r > qg) s[qo][jm][r] = -3e38f;
            }
          }
        }
        // ---- p = exp2(s), pack via v_perm ----
        s16x4 pk[2][4];
#pragma unroll
        for (int qo = 0; qo < 2; ++qo)
#pragma unroll
          for (int jm = 0; jm < 4; ++jm) {
            float p0 = __builtin_amdgcn_exp2f(s[qo][jm][0]);
            float p1 = __builtin_amdgcn_exp2f(s[qo][jm][1]);
            float p2 = __builtin_amdgcn_exp2f(s[qo][jm][2]);
            float p3 = __builtin_amdgcn_exp2f(s[qo][jm][3]);
            u32x2 w2;
            w2[0] = pkb(p0, p1);
            w2[1] = pkb(p2, p3);
            pk[qo][jm] = __builtin_bit_cast(s16x4, w2);
          }
        // ---- O += P V; l += P 1 (both MFMA) ----
        __builtin_amdgcn_s_setprio(1);
#if HAVE_MFMA16
        const s16x4 ones = {16256, 16256, 16256, 16256};  // bf16 1.0
#pragma unroll
        for (int js = 0; js < 4; ++js) {
          lacc[0] = mfma16(pk[0][js], ones, lacc[0]);
          lacc[1] = mfma16(pk[1][js], ones, lacc[1]);
#pragma unroll
          for (int jd = 0; jd < 4; ++jd) {
            s16x4 vf = *(const s16x4*)&bufc[(jd * 16 + ln15) * 64 +
                                            (((js * 4 + quad) ^ ln15) << 2)];
            o[0][jd] = mfma16(pk[0][js], vf, o[0][jd]);
            o[1][jd] = mfma16(pk[1][js], vf, o[1][jd]);
          }
        }
#else
        const s16x8 ones8 = {16256, 16256, 16256, 16256,
                             16256, 16256, 16256, 16256};
#pragma unroll
        for (int ks = 0; ks < 2; ++ks) {
          s16x8 a0 = repack(pk[0][2 * ks], pk[0][2 * ks + 1], quad, ln15);
          s16x8 a1 = repack(pk[1][2 * ks], pk[1][2 * ks + 1], quad, ln15);
          lacc[0] = mfma32(a0, ones8, lacc[0]);
          lacc[1] = mfma32(a1, ones8, lacc[1]);
#pragma unroll
          for (int jd = 0; jd < 4; ++jd) {
            int row = (jd * 16 + ln15) * 64;
            int g0 = ks * 8 + quad * 2;
            u64x2 tv;
            tv[0] = *(const unsigned long long*)&bufc[row + ((g0 ^ ln15) << 2)];
            tv[1] =
                *(const unsigned long long*)&bufc[row + (((g0 + 1) ^ ln15) << 2)];
            s16x8 vf = __builtin_bit_cast(s16x8, tv);
            o[0][jd] = mfma32(a0, vf, o[0][jd]);
            o[1][jd] = mfma32(a1, vf, o[1][jd]);
          }
        }
#endif
        __builtin_amdgcn_s_setprio(0);
      }
      // write prefetched V tile -> other buffer (granule-swizzled)
      if (nxt) {
        short* bufn = sVt[(kt + 1) & 1];
#pragma unroll
        for (int i = 0; i < 2; ++i) {
          int d0 = dgrp * 4 + i * 32;
#pragma unroll
          for (int u = 0; u < 4; ++u) {
            unsigned w = (unsigned)(unsigned short)va[i][u] |
                         ((unsigned)(unsigned short)vbr[i][u] << 16);
            int dd = d0 + u;
            *(unsigned*)&bufn[dd * 64 + (((tp >> 1) ^ (dd & 15)) << 2) +
                              ((tp & 1) << 1)] = w;
          }
        }
      }
    }
    // epilogue: rows q=quad*4+r, cols d=jd*16+ln15; l per-lane from lacc
#pragma unroll
    for (int qo = 0; qo < 2; ++qo)
#pragma unroll
      for (int r = 0; r < 4; ++r) {
        float linv = 1.f / lacc[qo][r];
        int qg = qw + qo * 16 + quad * 4 + r;
        size_t row = ((size_t)b * 2048 + qg) * 1024 + h * 64;
#pragma unroll
        for (int jd = 0; jd < 4; ++jd)
          Aout[row + jd * 16 + ln15] = f2b(o[qo][jd][r] * linv);
      }
  }
}

extern "C" void kernel_launch(void* const* d_in, const int* in_sizes, int n_in,
                              void* d_out, int out_size, void* d_ws, size_t ws_size,
                              hipStream_t stream) {
  const float* x  = (const float*)d_in[0];
  const float* wq = (const float*)d_in[1];
  const float* wk = (const float*)d_in[2];
  const float* wv = (const float*)d_in[3];
  const float* wo = (const float*)d_in[4];
  char* ws = (char*)d_ws;
  short* xb    = (short*)(ws);
  short* wqkvb = (short*)(ws + 16777216);
  short* wob   = (short*)(ws + 23068672);
  short* qkv   = (short*)(ws + 25165824);
  short* attn  = xb;  // x dead after QKV GEMM

  convert_all<<<12288, 256, 0, stream>>>(x, wq, wk, wv, wo, xb, wqkvb, wob);
  gemm_bt<0><<<dim3(24, 64), 256, 0, stream>>>(xb, wqkvb, nullptr, qkv,
                                               8192, 3072, 1024);
  attn_fa<<<512, 256, 0, stream>>>(qkv, qkv + 8388608, qkv + 16777216, attn);
  gemm_bt<1><<<dim3(8, 64), 256, 0, stream>>>(attn, wob, (float*)d_out, nullptr,
                                              8192, 1024, 1024);
}

// Round 8
// 251.298 us; speedup vs baseline: 1.3990x; 1.2842x over previous
//
#include <hip/hip_runtime.h>

typedef __attribute__((ext_vector_type(8))) short s16x8;
typedef __attribute__((ext_vector_type(4))) short s16x4;
typedef __attribute__((ext_vector_type(4))) float f32x4;
typedef __attribute__((ext_vector_type(8))) __bf16 bf16x8;
typedef __attribute__((ext_vector_type(2))) unsigned u32x2;
typedef __attribute__((ext_vector_type(2))) unsigned long long u64x2;

// fp32 -> bf16 round-to-nearest-even
__device__ __forceinline__ short f2b(float f) {
  unsigned u = __float_as_uint(f);
  u += 0x7fffu + ((u >> 16) & 1u);
  return (short)(u >> 16);
}

// pack two fp32 -> two bf16 (truncate) in ONE v_perm_b32
__device__ __forceinline__ unsigned pkb(float lo, float hi) {
  return __builtin_amdgcn_perm(__float_as_uint(hi), __float_as_uint(lo),
                               0x07060302u);
}

__device__ __forceinline__ f32x4 mfma32(s16x8 a, s16x8 b, f32x4 c) {
  return __builtin_amdgcn_mfma_f32_16x16x32_bf16(
      __builtin_bit_cast(bf16x8, a), __builtin_bit_cast(bf16x8, b), c, 0, 0, 0);
}

#if __has_builtin(__builtin_amdgcn_mfma_f32_16x16x16bf16_1k)
#define HAVE_MFMA16 1
__device__ __forceinline__ f32x4 mfma16(s16x4 a, s16x4 b, f32x4 c) {
  return __builtin_amdgcn_mfma_f32_16x16x16bf16_1k(a, b, c, 0, 0, 0);
}
#else
#define HAVE_MFMA16 0
// repack P (S^T C-layout regs, k=16j+quad*4+r) into 16x16x32 A-frag (k=quad*8+c)
__device__ __forceinline__ s16x8 repack(s16x4 pa, s16x4 pb, int quad, int ln15) {
  unsigned long long a = __builtin_bit_cast(unsigned long long, pa);
  unsigned long long bq = __builtin_bit_cast(unsigned long long, pb);
  int srcLo = ((quad & 1) << 5) | ln15;
  unsigned long long loa = __shfl(a, srcLo);
  unsigned long long lob = __shfl(bq, srcLo);
  unsigned long long hia = __shfl(a, srcLo + 16);
  unsigned long long hib = __shfl(bq, srcLo + 16);
  u64x2 t;
  t[0] = quad < 2 ? loa : lob;
  t[1] = quad < 2 ? hia : hib;
  return __builtin_bit_cast(s16x8, t);
}
#endif

// ---------------- convert fp32 -> bf16 (x, Wq|Wk|Wv concat, Wo) ----------------
__global__ __launch_bounds__(256) void convert_all(
    const float* __restrict__ x, const float* __restrict__ wq,
    const float* __restrict__ wk, const float* __restrict__ wv,
    const float* __restrict__ wo, short* __restrict__ xb,
    short* __restrict__ wqkvb, short* __restrict__ wob) {
  size_t i4 = ((size_t)blockIdx.x * 256 + threadIdx.x) * 4;
  const float* src;
  short* dst;
  size_t off;
  if (i4 < 8388608) {
    src = x; dst = xb; off = i4;
  } else if (i4 < 9437184) {
    src = wq; dst = wqkvb; off = i4 - 8388608;
  } else if (i4 < 10485760) {
    src = wk; dst = wqkvb + 1048576; off = i4 - 9437184;
  } else if (i4 < 11534336) {
    src = wv; dst = wqkvb + 2097152; off = i4 - 10485760;
  } else {
    src = wo; dst = wob; off = i4 - 11534336;
  }
  float4 f = *(const float4*)(src + off);
  s16x4 o;
  o[0] = f2b(f.x); o[1] = f2b(f.y); o[2] = f2b(f.z); o[3] = f2b(f.w);
  *(s16x4*)(dst + off) = o;
}

// ---------------- GEMM: C[M,N] = A[M,K] * B[N,K]^T -------------------------
// BK=64 (halves barrier/vmcnt drains vs BK=32 m97 structure, LDS still fits
// the 33.8KB epilogue overlay -> no occupancy cost). A/B tiles staged via
// global_load_lds with XOR granule swizzle (linear [128][64] would be a
// 16-way bank conflict on ds_read_b128: every 128B row starts at bank 0).
// Read-side XOR key = ln15&7 is thread-constant -> folds into base address.
__device__ __forceinline__ void stage_tile(const short* __restrict__ g, int ld,
                                           int row0, int k0, short* lds,
                                           int wid, int lane) {
  // tile 128x64 shorts = 1024 granules of 16B; 4 per thread.
  // LDS linear dest; source granule XOR-swizzled: LDS[row][j] = G[row][j^(row&7)]
#pragma unroll
  for (int i = 0; i < 4; ++i) {
    int gr = i * 256 + wid * 64 + lane;  // granule id 0..1023
    int row = gr >> 3;
    int sg = (gr & 7) ^ (row & 7);
    const short* gp = g + (size_t)(row0 + row) * ld + k0 + sg * 8;
    __builtin_amdgcn_global_load_lds(
        (const __attribute__((address_space(1))) void*)gp,
        (__attribute__((address_space(3))) void*)(lds + i * 2048 + wid * 512),
        16, 0, 0);
  }
}

// EPI 0: scatter QKV -> Q (pre-scaled by log2e/8), K, V, all bf16 [B,H,T,D],
//        via LDS-coalesced epilogue (16B contiguous stores).
// EPI 1: fp32 direct store.
template <int EPI>
__global__ __launch_bounds__(256) void gemm_bt(
    const short* __restrict__ A, const short* __restrict__ Bw,
    float* __restrict__ outf, short* __restrict__ qkv,
    int M, int N, int K) {
  // overlay: lA/lB (32 KB) for K-loop; lC (128x132 shorts = 33 KB) for epilogue
  __shared__ __align__(16) char smem[EPI == 0 ? 128 * 132 * 2 : 32768];
  short* lA = (short*)smem;
  short* lB = lA + 8192;
  const int tid = threadIdx.x;
  const int lane = tid & 63, wid = tid >> 6;
  const int quad = lane >> 4, ln15 = lane & 15;
  const int kx = ln15 & 7;  // staging-swizzle read key
  const int wm = wid & 1, wn = wid >> 1;
  // XCD-contiguous tile remap (bijective; nwg divisible by 8): XCD x gets
  // tiles [x*cpx,(x+1)*cpx) -> 8 consecutive M-panel rows share L2-local A.
  const int gx = (int)gridDim.x;
  const int lin = (int)blockIdx.y * gx + (int)blockIdx.x;
  const int cpx = (gx * (int)gridDim.y) >> 3;
  const int t = (lin & 7) * cpx + (lin >> 3);
  const int m0 = (t / gx) * 128, n0 = (t % gx) * 128;

  f32x4 acc[4][4] = {};

  stage_tile(A, K, m0, 0, lA, wid, lane);
  stage_tile(Bw, K, n0, 0, lB, wid, lane);

  const int nk = K >> 6;
  for (int kt = 0; kt < nk; ++kt) {
    __syncthreads();
#pragma unroll
    for (int h = 0; h < 2; ++h) {
      s16x8 af[4], bf[4];
#pragma unroll
      for (int i = 0; i < 4; ++i)
        af[i] = *(const s16x8*)&lA[(wm * 64 + i * 16 + ln15) * 64 +
                                   (((h << 2) + quad) ^ kx) * 8];
#pragma unroll
      for (int j = 0; j < 4; ++j)
        bf[j] = *(const s16x8*)&lB[(wn * 64 + j * 16 + ln15) * 64 +
                                   (((h << 2) + quad) ^ kx) * 8];
#pragma unroll
      for (int i = 0; i < 4; ++i)
#pragma unroll
        for (int j = 0; j < 4; ++j)
          acc[i][j] = mfma32(af[i], bf[j], acc[i][j]);
    }
    __syncthreads();
    if (kt + 1 < nk) {
      stage_tile(A, K, m0, (kt + 1) << 6, lA, wid, lane);
      stage_tile(Bw, K, n0, (kt + 1) << 6, lB, wid, lane);
    }
  }

  if (EPI == 1) {
#pragma unroll
    for (int i = 0; i < 4; ++i)
#pragma unroll
      for (int j = 0; j < 4; ++j)
#pragma unroll
        for (int r = 0; r < 4; ++r) {
          int m = m0 + wm * 64 + i * 16 + quad * 4 + r;
          int n = n0 + wn * 64 + j * 16 + ln15;
          outf[(size_t)m * N + n] = acc[i][j][r];
        }
  } else {
    const float QSC = 0.18033688f;  // (1/sqrt(64)) * log2(e), folded into Q
    const int which = n0 >> 10;     // whole 128-tile within one of Q/K/V
    const float sf = (which == 0) ? QSC : 1.0f;
    short* lC = (short*)smem;
    __syncthreads();  // all waves done with lA/lB ds_reads
#pragma unroll
    for (int i = 0; i < 4; ++i)
#pragma unroll
      for (int j = 0; j < 4; ++j) {
        int mm = wm * 64 + i * 16 + quad * 4;
        int nn = wn * 64 + j * 16 + ln15;
#pragma unroll
        for (int r = 0; r < 4; ++r)
          lC[(mm + r) * 132 + nn] = f2b(acc[i][j][r] * sf);
      }
    __syncthreads();
    short* outb = qkv + (size_t)which * 8388608;
#pragma unroll
    for (int r0 = 0; r0 < 8; ++r0) {
      int m = r0 * 16 + (tid >> 4);
      int ncol = (tid & 15) * 8;
      s16x4 lo = *(const s16x4*)&lC[m * 132 + ncol];
      s16x4 hi = *(const s16x4*)&lC[m * 132 + ncol + 4];
      s16x8 v8;
#pragma unroll
      for (int z = 0; z < 4; ++z) { v8[z] = lo[z]; v8[4 + z] = hi[z]; }
      int n = n0 + ncol;
      int mg = m0 + m;
      int bidx = mg >> 11, tt = mg & 2047;
      int hh = (n >> 6) & 15, d0 = n & 63;
      *(s16x8*)&outb[(size_t)((((bidx << 4) + hh) << 11) + tt) * 64 + d0] = v8;
    }
  }
}

// ---------------- flash attention, S^T form, fixed-max ----------------------
// EXACT r3 kernel (best verified: 82us attn). Intra-block causal pairing:
// per (b,h), 16 chunks of 128 q rows; block handles (15-p, p) as two phases
// -> identical work per block, robust to undefined block->CU mapping.
// 512 blocks, 4 waves x 32 q rows. K staged via global_load_lds DMA
// (double-buffered, XOR-swizzled source so ds_read_b128 is conflict-free).
// V reg-prefetched then written transposed [d][t pad72], double-buffered.
// (V-layout experiments r4/r6/r7 all regressed: VST=74 breaks b64 alignment,
// granule-XOR defeats immediate-offset folding + spills. VST=72's 4.3M
// conflict-cycles cost <=5us -- keep.)
// Fixed max: Q pre-scaled by log2e/8 -> p = exp2(s). l via MFMA vs ones.
__device__ __forceinline__ void stage_k(const short* __restrict__ Kb, int t,
                                        short* sbuf, int wid, int lane) {
  // LDS linear dest; source granule XOR-swizzled: LDS[row][j] = K[row][j^(row&7)]
#pragma unroll
  for (int i = 0; i < 2; ++i) {
    int g = wid * 128 + i * 64 + lane;      // 16B granule index, 512 total
    int row = g >> 3;
    int sg = (g & 7) ^ (row & 7);
    const short* gp = Kb + (size_t)(t * 64 + row) * 64 + sg * 8;
    __builtin_amdgcn_global_load_lds(
        (const __attribute__((address_space(1))) void*)gp,
        (__attribute__((address_space(3))) void*)(sbuf + wid * 1024 + i * 512),
        16, 0, 0);
  }
}

__global__ __launch_bounds__(256, 4) void attn_fa(
    const short* __restrict__ Q, const short* __restrict__ K,
    const short* __restrict__ V, short* __restrict__ Aout) {
  __shared__ __align__(16) short sVt[2][64 * 72];  // 18.4 KB
  __shared__ __align__(16) short sK[2][64 * 64];   // 16 KB
  const int tid = threadIdx.x;
  const int lane = tid & 63, wid = tid >> 6;
  const int quad = lane >> 4, ln15 = lane & 15;
  const int e3 = ln15 & 7;
  const int bx = blockIdx.x;
  const int bh = bx & 63;  // bh-minor: all blocks of a bh land on one XCD's L2
  const int p = bx >> 6;   // 0..7
  const short* Qb = Q + (size_t)bh * 131072;
  const short* Kb = K + (size_t)bh * 131072;
  const short* Vb = V + (size_t)bh * 131072;
  const int b = bh >> 4, h = bh & 15;
  const int tp = tid & 31, dgrp = tid >> 5;  // V staging: t=2tp,2tp+1; d0=dgrp*4

  for (int ph = 0; ph < 2; ++ph) {
    const int c = ph ? p : (15 - p);         // chunk id (128 q rows)
    const int nkv = 2 * c + 2;               // uniform barrier count
    const int ntw = 2 * c + 1 + (wid >> 1);  // this wave's live tiles
    const int qw = c * 128 + wid * 32;       // this wave's 32 q rows

    // Q fragments for this chunk
    s16x8 qf[2][2];
#pragma unroll
    for (int qo = 0; qo < 2; ++qo)
#pragma unroll
      for (int ks = 0; ks < 2; ++ks)
        qf[qo][ks] =
            *(const s16x8*)&Qb[(qw + qo * 16 + ln15) * 64 + ks * 32 + quad * 8];

    f32x4 o[2][4] = {};
    f32x4 lacc[2] = {};

    __syncthreads();  // prior phase's LDS reads done before restaging
    // stage V tile 0 -> buf 0 (transposed, packed b32 writes)
#pragma unroll
    for (int i = 0; i < 2; ++i) {
      int d0 = dgrp * 4 + i * 32;
      s16x4 va0 = *(const s16x4*)&Vb[(2 * tp) * 64 + d0];
      s16x4 vb0 = *(const s16x4*)&Vb[(2 * tp + 1) * 64 + d0];
#pragma unroll
      for (int u = 0; u < 4; ++u) {
        unsigned w = (unsigned)(unsigned short)va0[u] |
                     ((unsigned)(unsigned short)vb0[u] << 16);
        *(unsigned*)&sVt[0][(d0 + u) * 72 + 2 * tp] = w;
      }
    }
    // DMA K tile 0 -> buf 0 (drained by first in-loop barrier)
    stage_k(Kb, 0, sK[0], wid, lane);

    for (int kt = 0; kt < nkv; ++kt) {
      __syncthreads();  // drains K DMA (vmcnt0) + makes V writes visible
      const short* bufc = sVt[kt & 1];
      const short* kbuf = sK[kt & 1];
      const bool nxt = (kt + 1 < nkv);
      // prefetch next V tile into regs + DMA next K tile
      s16x4 va[2], vbr[2];
      if (nxt) {
#pragma unroll
        for (int i = 0; i < 2; ++i) {
          int d0 = dgrp * 4 + i * 32;
          va[i] = *(const s16x4*)&Vb[((kt + 1) * 64 + 2 * tp) * 64 + d0];
          vbr[i] = *(const s16x4*)&Vb[((kt + 1) * 64 + 2 * tp + 1) * 64 + d0];
        }
        stage_k(Kb, kt + 1, sK[(kt + 1) & 1], wid, lane);
      }
      if (kt < ntw) {
        __builtin_amdgcn_s_setprio(1);
        // ---- S^T = K Q^T (K from swizzled LDS) ----
        f32x4 s[2][4] = {};
#pragma unroll
        for (int jm = 0; jm < 4; ++jm) {
          const short* kr = &kbuf[(jm * 16 + ln15) * 64];
          s16x8 k0 = *(const s16x8*)&kr[(quad ^ e3) * 8];
          s16x8 k1 = *(const s16x8*)&kr[((4 + quad) ^ e3) * 8];
          s[0][jm] = mfma32(k0, qf[0][0], s[0][jm]);
          s[0][jm] = mfma32(k1, qf[0][1], s[0][jm]);
          s[1][jm] = mfma32(k0, qf[1][0], s[1][jm]);
          s[1][jm] = mfma32(k1, qf[1][1], s[1][jm]);
        }
        __builtin_amdgcn_s_setprio(0);
        // ---- causal mask (diagonal tile only) ----
        if (kt == ntw - 1) {
#pragma unroll
          for (int qo = 0; qo < 2; ++qo) {
            int qg = qw + qo * 16 + ln15;
#pragma unroll
            for (int jm = 0; jm < 4; ++jm) {
              int kg = kt * 64 + jm * 16 + quad * 4;
#pragma unroll
              for (int r = 0; r < 4; ++r)
                if (kg + r > qg) s[qo][jm][r] = -3e38f;
            }
          }
        }
        // ---- p = exp2(s), pack via v_perm ----
        s16x4 pk[2][4];
#pragma unroll
        for (int qo = 0; qo < 2; ++qo)
#pragma unroll
          for (int jm = 0; jm < 4; ++jm) {
            float p0 = __builtin_amdgcn_exp2f(s[qo][jm][0]);
            float p1 = __builtin_amdgcn_exp2f(s[qo][jm][1]);
            float p2 = __builtin_amdgcn_exp2f(s[qo][jm][2]);
            float p3 = __builtin_amdgcn_exp2f(s[qo][jm][3]);
            u32x2 w2;
            w2[0] = pkb(p0, p1);
            w2[1] = pkb(p2, p3);
            pk[qo][jm] = __builtin_bit_cast(s16x4, w2);
          }
        // ---- O += P V; l += P 1 (both MFMA) ----
        __builtin_amdgcn_s_setprio(1);
#if HAVE_MFMA16
        const s16x4 ones = {16256, 16256, 16256, 16256};  // bf16 1.0
#pragma unroll
        for (int js = 0; js < 4; ++js) {
          lacc[0] = mfma16(pk[0][js], ones, lacc[0]);
          lacc[1] = mfma16(pk[1][js], ones, lacc[1]);
#pragma unroll
          for (int jd = 0; jd < 4; ++jd) {
            s16x4 vf =
                *(const s16x4*)&bufc[(jd * 16 + ln15) * 72 + js * 16 + quad * 4];
            o[0][jd] = mfma16(pk[0][js], vf, o[0][jd]);
            o[1][jd] = mfma16(pk[1][js], vf, o[1][jd]);
          }
        }
#else
        const s16x8 ones8 = {16256, 16256, 16256, 16256,
                             16256, 16256, 16256, 16256};
#pragma unroll
        for (int ks = 0; ks < 2; ++ks) {
          s16x8 a0 = repack(pk[0][2 * ks], pk[0][2 * ks + 1], quad, ln15);
          s16x8 a1 = repack(pk[1][2 * ks], pk[1][2 * ks + 1], quad, ln15);
          lacc[0] = mfma32(a0, ones8, lacc[0]);
          lacc[1] = mfma32(a1, ones8, lacc[1]);
#pragma unroll
          for (int jd = 0; jd < 4; ++jd) {
            s16x8 vf =
                *(const s16x8*)&bufc[(jd * 16 + ln15) * 72 + ks * 32 + quad * 8];
            o[0][jd] = mfma32(a0, vf, o[0][jd]);
            o[1][jd] = mfma32(a1, vf, o[1][jd]);
          }
        }
#endif
        __builtin_amdgcn_s_setprio(0);
      }
      // write prefetched V tile -> other buffer
      if (nxt) {
        short* bufn = sVt[(kt + 1) & 1];
#pragma unroll
        for (int i = 0; i < 2; ++i) {
          int d0 = dgrp * 4 + i * 32;
#pragma unroll
          for (int u = 0; u < 4; ++u) {
            unsigned w = (unsigned)(unsigned short)va[i][u] |
                         ((unsigned)(unsigned short)vbr[i][u] << 16);
            *(unsigned*)&bufn[(d0 + u) * 72 + 2 * tp] = w;
          }
        }
      }
    }
    // epilogue: rows q=quad*4+r, cols d=jd*16+ln15; l per-lane from lacc
#pragma unroll
    for (int qo = 0; qo < 2; ++qo)
#pragma unroll
      for (int r = 0; r < 4; ++r) {
        float linv = 1.f / lacc[qo][r];
        int qg = qw + qo * 16 + quad * 4 + r;
        size_t row = ((size_t)b * 2048 + qg) * 1024 + h * 64;
#pragma unroll
        for (int jd = 0; jd < 4; ++jd)
          Aout[row + jd * 16 + ln15] = f2b(o[qo][jd][r] * linv);
      }
  }
}

extern "C" void kernel_launch(void* const* d_in, const int* in_sizes, int n_in,
                              void* d_out, int out_size, void* d_ws, size_t ws_size,
                              hipStream_t stream) {
  const float* x  = (const float*)d_in[0];
  const float* wq = (const float*)d_in[1];
  const float* wk = (const float*)d_in[2];
  const float* wv = (const float*)d_in[3];
  const float* wo = (const float*)d_in[4];
  char* ws = (char*)d_ws;
  short* xb    = (short*)(ws);
  short* wqkvb = (short*)(ws + 16777216);
  short* wob   = (short*)(ws + 23068672);
  short* qkv   = (short*)(ws + 25165824);
  short* attn  = xb;  // x dead after QKV GEMM

  convert_all<<<12288, 256, 0, stream>>>(x, wq, wk, wv, wo, xb, wqkvb, wob);
  gemm_bt<0><<<dim3(24, 64), 256, 0, stream>>>(xb, wqkvb, nullptr, qkv,
                                               8192, 3072, 1024);
  attn_fa<<<512, 256, 0, stream>>>(qkv, qkv + 8388608, qkv + 16777216, attn);
  gemm_bt<1><<<dim3(8, 64), 256, 0, stream>>>(attn, wob, (float*)d_out, nullptr,
                                              8192, 1024, 1024);
}